// Round 4
// baseline (3359.109 us; speedup 1.0000x reference)
//
#include <hip/hip_runtime.h>
#include <hip/hip_bf16.h>

// Problem constants (from reference)
#define NUME 100000
constexpr int H      = 4;
constexpr int DH     = 32;
constexpr int KNB    = 16;     // neighbors per dst
constexpr int R      = 17;     // relations
constexpr int DIN    = 128;
constexpr int DT     = 32;
constexpr int DINT   = 160;    // DIN + DT
constexpr int N0     = 131072;
constexpr int N1     = 32768;
constexpr int N2     = 4096;
constexpr float LN_EPS = 1e-5f;

typedef unsigned short ushort_t;
typedef ushort_t us8 __attribute__((ext_vector_type(8)));

__device__ __forceinline__ float bf2f(ushort_t u) {
    return __uint_as_float(((unsigned int)u) << 16);
}
__device__ __forceinline__ ushort_t f2bf(float f) {   // round-to-nearest-even
    unsigned int x = __float_as_uint(f);
    unsigned int r = x + 0x7fffu + ((x >> 16) & 1u);
    return (ushort_t)(r >> 16);
}

// -------------------------------------------------------------------------
// K1: [optional relu(x/R)] + time-enc + concat + LayerNorm. One wave per row.
// mode=1: row = emb[ids[n] % NUME]              (layer 0)
// mode=0: row = relu(srcf[n]/R)                 (layer 1: srcf = layer-0 acc)
// Output hn is bf16 [n_rows,160].
// -------------------------------------------------------------------------
__global__ __launch_bounds__(256) void k_prep(
    const float* __restrict__ srcf,
    const int*   __restrict__ ids,
    const int*   __restrict__ ts_ptr,
    const float* __restrict__ freq,
    const float* __restrict__ phase,
    const float* __restrict__ gamma,
    const float* __restrict__ beta,
    ushort_t*    __restrict__ hn,
    int n_rows, int mode)
{
    int wid  = (int)((blockIdx.x * blockDim.x + threadIdx.x) >> 6);
    int lane = threadIdx.x & 63;
    if (wid >= n_rows) return;

    int id = ids[wid];
    const float* row = (mode == 1)
        ? (srcf + (size_t)(id % NUME) * DIN)
        : (srcf + (size_t)wid * DIN);

    float x0 = row[lane];
    float x1 = row[lane + 64];
    if (mode == 0) {
        x0 = fmaxf(x0 * (1.f / (float)R), 0.f);
        x1 = fmaxf(x1 * (1.f / (float)R), 0.f);
    }

    int   ts = ts_ptr[0];
    float t  = (float)(ts - id / NUME);
    float p  = 0.f;
    if (lane < DT) p = cosf(t * freq[lane] + phase[lane]);

    float s  = x0 + x1 + p;
    float sq = x0*x0 + x1*x1 + p*p;
    #pragma unroll
    for (int m = 1; m < 64; m <<= 1) {
        s  += __shfl_xor(s,  m);
        sq += __shfl_xor(sq, m);
    }
    float mu   = s / (float)DINT;
    float var  = sq / (float)DINT - mu * mu;
    float rstd = rsqrtf(var + LN_EPS);

    size_t base = (size_t)wid * DINT;
    hn[base + lane]      = f2bf((x0 - mu) * rstd * gamma[lane]      + beta[lane]);
    hn[base + 64 + lane] = f2bf((x1 - mu) * rstd * gamma[64 + lane] + beta[64 + lane]);
    if (lane < DT)
        hn[base + 128 + lane] = f2bf((p - mu) * rstd * gamma[128 + lane] + beta[128 + lane]);
}

// -------------------------------------------------------------------------
// K2: GEMM  proj[M,128](bf16) = hn[M,160](bf16) @ Wr[160,128](f32)
// Block tile 128x128, K staged in chunks of 32, f32 math in LDS/registers.
// 256 threads, 8x8 per thread.
// -------------------------------------------------------------------------
__global__ __launch_bounds__(256) void k_gemm(
    const ushort_t* __restrict__ A,    // [M,160] bf16
    const float*    __restrict__ Bw,   // [160,128] f32 (relation slice)
    ushort_t*       __restrict__ C,    // [M,128] bf16
    int M)
{
    __shared__ float As[32][132];   // [k][m], padded
    __shared__ float Bs[32][128];   // [k][n]

    int tid = threadIdx.x;
    int tm  = tid >> 4;             // 0..15 -> rows tm*8..+7
    int tn  = tid & 15;             // 0..15 -> cols tn*8..+7
    int row0 = blockIdx.x * 128;

    float acc[8][8];
    #pragma unroll
    for (int i = 0; i < 8; ++i)
        #pragma unroll
        for (int j = 0; j < 8; ++j) acc[i][j] = 0.f;

    for (int kc = 0; kc < DINT; kc += 32) {
        // stage A: 128 rows x 32 k (bf16 -> f32), transposed to [k][m]
        #pragma unroll
        for (int j = 0; j < 2; ++j) {
            int f  = tid + j * 256;        // 0..511 us8-groups
            int m  = f >> 2;               // 0..127
            int ko = (f & 3) * 8;          // 0,8,16,24
            us8 a8 = *(const us8*)&A[(size_t)(row0 + m) * DINT + kc + ko];
            #pragma unroll
            for (int i = 0; i < 8; ++i) As[ko + i][m] = bf2f(a8[i]);
        }
        // stage B: 32 k x 128 n f32.  4096 floats = 1024 float4s -> j<4 (BUGFIX)
        #pragma unroll
        for (int j = 0; j < 4; ++j) {
            int f  = tid + j * 256;        // 0..1023
            int kk = f >> 5;               // 0..31
            int nq = f & 31;               // 0..31
            *(float4*)&Bs[kk][nq * 4] = *(const float4*)&Bw[(size_t)(kc + kk) * 128 + nq * 4];
        }
        __syncthreads();

        #pragma unroll
        for (int k = 0; k < 32; ++k) {
            float a[8], b[8];
            *(float4*)&a[0] = *(const float4*)&As[k][tm*8];
            *(float4*)&a[4] = *(const float4*)&As[k][tm*8 + 4];
            *(float4*)&b[0] = *(const float4*)&Bs[k][tn*8];
            *(float4*)&b[4] = *(const float4*)&Bs[k][tn*8 + 4];
            #pragma unroll
            for (int i = 0; i < 8; ++i)
                #pragma unroll
                for (int j = 0; j < 8; ++j)
                    acc[i][j] = fmaf(a[i], b[j], acc[i][j]);
        }
        __syncthreads();
    }

    #pragma unroll
    for (int i = 0; i < 8; ++i) {
        us8 p;
        #pragma unroll
        for (int j = 0; j < 8; ++j) p[j] = f2bf(acc[i][j]);
        *(us8*)&C[(size_t)(row0 + tm*8 + i) * 128 + tn*8] = p;
    }
}

// -------------------------------------------------------------------------
// K3: edge attention + aggregate, one wave per dst node.
// lane = 4*kq + g : kq = neighbor slot (0..15), g = head (0..3).
// proj is bf16; al/ar/br are f32 inputs; acc is f32.
// -------------------------------------------------------------------------
__global__ __launch_bounds__(256) void k_agg(
    const ushort_t* __restrict__ proj,   // [Nsrc,128] bf16
    const int*      __restrict__ idx,    // [ndst,16] (relation slice)
    const float*    __restrict__ al,     // [128] f32 (relation slice)
    const float*    __restrict__ ar,     // [128]
    const float*    __restrict__ br,     // [128]
    float*          __restrict__ acc,    // [ndst,128] f32, accumulated over R
    int ndst)
{
    int wid  = (int)((blockIdx.x * blockDim.x + threadIdx.x) >> 6);
    if (wid >= ndst) return;
    int lane = threadIdx.x & 63;
    int kq = lane >> 2;
    int g  = lane & 3;

    int j = idx[(size_t)wid * KNB + kq];

    const ushort_t* prow = proj + (size_t)j   * 128 + g * 32;
    const ushort_t* drow = proj + (size_t)wid * 128 + g * 32;
    const float*    alg  = al + g * 32;
    const float*    arg  = ar + g * 32;

    float v[32];
    float el = 0.f, er = 0.f;
    #pragma unroll
    for (int c = 0; c < 4; ++c) {
        us8 p8 = *(const us8*)&prow[c * 8];
        us8 d8 = *(const us8*)&drow[c * 8];
        #pragma unroll
        for (int i = 0; i < 8; ++i) {
            int e = c * 8 + i;
            float pv = bf2f(p8[i]);
            v[e] = pv;
            el += pv * alg[e];
            er += bf2f(d8[i]) * arg[e];
        }
    }

    float e = el + er;
    e = e > 0.f ? e : 0.2f * e;          // leaky_relu(., 0.2)

    float mx = e;
    #pragma unroll
    for (int m = 4; m < 64; m <<= 1) mx = fmaxf(mx, __shfl_xor(mx, m));
    float p = expf(e - mx);
    float s = p;
    #pragma unroll
    for (int m = 4; m < 64; m <<= 1) s += __shfl_xor(s, m);
    float a = p / s;                     // softmax over K (per head)

    #pragma unroll
    for (int q = 0; q < 32; ++q) v[q] *= a;
    // sum over the 16 neighbor slots (kq bits are lane bits 2..5)
    #pragma unroll
    for (int m = 4; m < 64; m <<= 1) {
        #pragma unroll
        for (int q = 0; q < 32; ++q) v[q] += __shfl_xor(v[q], m);
    }

    if (kq < 8) {
        int col = g * 32 + kq * 4;
        float4 b4 = *(const float4*)&br[col];
        float* ap = acc + (size_t)wid * 128 + col;
        float4 c  = *(float4*)ap;
        c.x += v[kq*4+0] + b4.x;
        c.y += v[kq*4+1] + b4.y;
        c.z += v[kq*4+2] + b4.z;
        c.w += v[kq*4+3] + b4.w;
        *(float4*)ap = c;
    }
}

// -------------------------------------------------------------------------
// K4: out[t] = relu(acc[root[t/128]][t%128] / R)   (final gather, f32 out)
// -------------------------------------------------------------------------
__global__ __launch_bounds__(256) void k_root(
    const float* __restrict__ acc, const int* __restrict__ root,
    float* __restrict__ out, int n)
{
    int t = blockIdx.x * blockDim.x + threadIdx.x;
    if (t < n) {
        float x = acc[(size_t)root[t >> 7] * 128 + (t & 127)];
        out[t] = fmaxf(x * (1.f / (float)R), 0.f);
    }
}

// -------------------------------------------------------------------------
extern "C" void kernel_launch(void* const* d_in, const int* in_sizes, int n_in,
                              void* d_out, int out_size, void* d_ws, size_t ws_size,
                              hipStream_t stream)
{
    const float* emb    = (const float*)d_in[0];
    const float* freq   = (const float*)d_in[1];
    const float* phase  = (const float*)d_in[2];
    const float* gamma0 = (const float*)d_in[3];
    const float* beta0  = (const float*)d_in[4];
    const float* W0     = (const float*)d_in[5];
    const float* al0    = (const float*)d_in[6];
    const float* ar0    = (const float*)d_in[7];
    const float* b0     = (const float*)d_in[8];
    const float* gamma1 = (const float*)d_in[9];
    const float* beta1  = (const float*)d_in[10];
    const float* W1     = (const float*)d_in[11];
    const float* al1    = (const float*)d_in[12];
    const float* ar1    = (const float*)d_in[13];
    const float* b1     = (const float*)d_in[14];
    const int* src_ids0 = (const int*)d_in[15];
    const int* src_idx0 = (const int*)d_in[16];
    const int* src_ids1 = (const int*)d_in[17];
    const int* src_idx1 = (const int*)d_in[18];
    const int* root     = (const int*)d_in[19];
    const int* ts       = (const int*)d_in[20];
    float* out = (float*)d_out;

    // workspace layout: hn bf16 [N0,160] | proj bf16 [N0,128] | acc f32 [N1,128]
    // = 41.9 MB + 33.6 MB + 16.8 MB = 92.3 MB
    ushort_t* hn   = (ushort_t*)d_ws;
    ushort_t* proj = hn + (size_t)N0 * DINT;
    float*    acc  = (float*)(proj + (size_t)N0 * DIN);

    // ---------------- layer 0 ----------------
    hipMemsetAsync(acc, 0, (size_t)N1 * DIN * sizeof(float), stream);
    k_prep<<<N0 / 4, 256, 0, stream>>>(emb, src_ids0, ts, freq, phase,
                                       gamma0, beta0, hn, N0, 1);
    for (int r = 0; r < R; ++r) {
        k_gemm<<<N0 / 128, 256, 0, stream>>>(hn, W0 + (size_t)r * DINT * DIN, proj, N0);
        k_agg<<<N1 / 4, 256, 0, stream>>>(proj,
                                          src_idx0 + (size_t)r * N1 * KNB,
                                          al0 + r * 128, ar0 + r * 128, b0 + r * 128,
                                          acc, N1);
    }

    // ---------------- layer 1 ----------------
    // prep reads layer-0 acc (applies relu(x/R) inline) BEFORE acc is reused
    k_prep<<<N1 / 4, 256, 0, stream>>>(acc, src_ids1, ts, freq, phase,
                                       gamma1, beta1, hn, N1, 0);
    hipMemsetAsync(acc, 0, (size_t)N2 * DIN * sizeof(float), stream);
    for (int r = 0; r < R; ++r) {
        k_gemm<<<N1 / 128, 256, 0, stream>>>(hn, W1 + (size_t)r * DINT * DIN, proj, N1);
        k_agg<<<N2 / 4, 256, 0, stream>>>(proj,
                                          src_idx1 + (size_t)r * N2 * KNB,
                                          al1 + r * 128, ar1 + r * 128, b1 + r * 128,
                                          acc, N2);
    }

    // ---------------- root gather (+ relu(x/R)) ----------------
    k_root<<<(N2 * DIN) / 256, 256, 0, stream>>>(acc, root, out, N2 * DIN);
}

// Round 5
// 1655.222 us; speedup vs baseline: 2.0294x; 2.0294x over previous
//
#include <hip/hip_runtime.h>
#include <hip/hip_bf16.h>

// Problem constants (from reference)
#define NUME 100000
constexpr int H      = 4;
constexpr int DH     = 32;
constexpr int KNB    = 16;     // neighbors per dst
constexpr int R      = 17;     // relations
constexpr int DIN    = 128;
constexpr int DT     = 32;
constexpr int DINT   = 160;    // DIN + DT
constexpr int N0     = 131072;
constexpr int N1     = 32768;
constexpr int N2     = 4096;
constexpr float LN_EPS = 1e-5f;

typedef unsigned short ushort_t;
typedef ushort_t us2 __attribute__((ext_vector_type(2)));
typedef ushort_t us8 __attribute__((ext_vector_type(8)));
typedef short    s8v __attribute__((ext_vector_type(8)));
typedef float    f32x4 __attribute__((ext_vector_type(4)));

__device__ __forceinline__ float bf2f(ushort_t u) {
    return __uint_as_float(((unsigned int)u) << 16);
}
__device__ __forceinline__ ushort_t f2bf(float f) {   // round-to-nearest-even
    unsigned int x = __float_as_uint(f);
    unsigned int r = x + 0x7fffu + ((x >> 16) & 1u);
    return (ushort_t)(r >> 16);
}

// -------------------------------------------------------------------------
// K0: W [R][160][128] f32  ->  wt [R][128][160] bf16 (transposed per rel)
// -------------------------------------------------------------------------
__global__ __launch_bounds__(256) void k_wcast(
    const float* __restrict__ W, ushort_t* __restrict__ wt, int total)
{
    int t = blockIdx.x * blockDim.x + threadIdx.x;
    if (t >= total) return;
    int r   = t / (DINT * DIN);
    int rem = t % (DINT * DIN);
    int k   = rem >> 7;            // 0..159
    int n   = rem & 127;           // 0..127
    wt[(size_t)r * DIN * DINT + (size_t)n * DINT + k] = f2bf(W[t]);
}

// -------------------------------------------------------------------------
// K1: [optional relu(x/R)] + time-enc + concat + LayerNorm. One wave per row.
// mode=1: row = emb[ids[n] % NUME]   (layer 0)
// mode=0: row = relu(srcf[n]/R)      (layer 1: srcf = layer-0 acc)
// -------------------------------------------------------------------------
__global__ __launch_bounds__(256) void k_prep(
    const float* __restrict__ srcf,
    const int*   __restrict__ ids,
    const int*   __restrict__ ts_ptr,
    const float* __restrict__ freq,
    const float* __restrict__ phase,
    const float* __restrict__ gamma,
    const float* __restrict__ beta,
    ushort_t*    __restrict__ hn,
    int n_rows, int mode)
{
    int wid  = (int)((blockIdx.x * blockDim.x + threadIdx.x) >> 6);
    int lane = threadIdx.x & 63;
    if (wid >= n_rows) return;

    int id = ids[wid];
    const float* row = (mode == 1)
        ? (srcf + (size_t)(id % NUME) * DIN)
        : (srcf + (size_t)wid * DIN);

    float x0 = row[lane];
    float x1 = row[lane + 64];
    if (mode == 0) {
        x0 = fmaxf(x0 * (1.f / (float)R), 0.f);
        x1 = fmaxf(x1 * (1.f / (float)R), 0.f);
    }

    int   ts = ts_ptr[0];
    float t  = (float)(ts - id / NUME);
    float p  = 0.f;
    if (lane < DT) p = cosf(t * freq[lane] + phase[lane]);

    float s  = x0 + x1 + p;
    float sq = x0*x0 + x1*x1 + p*p;
    #pragma unroll
    for (int m = 1; m < 64; m <<= 1) {
        s  += __shfl_xor(s,  m);
        sq += __shfl_xor(sq, m);
    }
    float mu   = s / (float)DINT;
    float var  = sq / (float)DINT - mu * mu;
    float rstd = rsqrtf(var + LN_EPS);

    size_t base = (size_t)wid * DINT;
    hn[base + lane]      = f2bf((x0 - mu) * rstd * gamma[lane]      + beta[lane]);
    hn[base + 64 + lane] = f2bf((x1 - mu) * rstd * gamma[64 + lane] + beta[64 + lane]);
    if (lane < DT)
        hn[base + 128 + lane] = f2bf((p - mu) * rstd * gamma[128 + lane] + beta[128 + lane]);
}

// -------------------------------------------------------------------------
// K2: MFMA GEMM  proj[M,128](bf16) = hn[M,160](bf16) @ wt^T  (wt is [128][160])
// 256 thr = 4 waves (2x2), tile 128x128, K chunks of 32, 16x16x32 bf16 MFMA.
// A-frag: lane&15 = m, (lane>>4)*8 = k-offset (8 contiguous k).
// B-frag: lane&15 = n, same k layout (from transposed wt).
// C/D  : col = lane&15, row = (lane>>4)*4 + q   [m89-verified]
// -------------------------------------------------------------------------
__global__ __launch_bounds__(256) void k_gemm(
    const ushort_t* __restrict__ A,    // [M,160] bf16
    const ushort_t* __restrict__ Bt,   // [128,160] bf16 (relation slice of wt)
    ushort_t*       __restrict__ C,    // [M,128] bf16
    int M)
{
    __shared__ ushort_t As[128][40];   // padded: stride 80 B (2-way bank max)
    __shared__ ushort_t Bs[128][40];

    int tid  = threadIdx.x;
    int lane = tid & 63;
    int wave = tid >> 6;
    int wr   = wave >> 1;              // 0..1: row half
    int wc   = wave & 1;               // 0..1: col half
    int row0 = blockIdx.x * 128;

    f32x4 acc[4][4];
    #pragma unroll
    for (int i = 0; i < 4; ++i)
        #pragma unroll
        for (int j = 0; j < 4; ++j) acc[i][j] = (f32x4){0.f, 0.f, 0.f, 0.f};

    for (int kc = 0; kc < DINT; kc += 32) {
        #pragma unroll
        for (int j = 0; j < 2; ++j) {
            int f  = tid + j * 256;          // 0..511
            int m  = f >> 2;                 // 0..127
            int ko = (f & 3) * 8;            // 0,8,16,24
            *(us8*)&As[m][ko] = *(const us8*)&A [(size_t)(row0 + m) * DINT + kc + ko];
            *(us8*)&Bs[m][ko] = *(const us8*)&Bt[(size_t)m          * DINT + kc + ko];
        }
        __syncthreads();

        s8v af[4], bf[4];
        #pragma unroll
        for (int i = 0; i < 4; ++i)
            af[i] = *(const s8v*)&As[wr*64 + i*16 + (lane & 15)][(lane >> 4) * 8];
        #pragma unroll
        for (int j = 0; j < 4; ++j)
            bf[j] = *(const s8v*)&Bs[wc*64 + j*16 + (lane & 15)][(lane >> 4) * 8];

        #pragma unroll
        for (int i = 0; i < 4; ++i)
            #pragma unroll
            for (int j = 0; j < 4; ++j)
                acc[i][j] = __builtin_amdgcn_mfma_f32_16x16x32_bf16(
                                af[i], bf[j], acc[i][j], 0, 0, 0);
        __syncthreads();
    }

    #pragma unroll
    for (int i = 0; i < 4; ++i) {
        #pragma unroll
        for (int j = 0; j < 4; ++j) {
            int col  = wc*64 + j*16 + (lane & 15);
            int rowb = row0 + wr*64 + i*16 + ((lane >> 4) << 2);
            #pragma unroll
            for (int q = 0; q < 4; ++q)
                C[(size_t)(rowb + q) * DIN + col] = f2bf(acc[i][j][q]);
        }
    }
}

// -------------------------------------------------------------------------
// K3: attention dots  el[n,h] = proj[n,h*32:+32] . al[h],  er likewise.
// One wave per row; lane owns 2 features; 4-round butterfly per 16-lane group.
// -------------------------------------------------------------------------
__global__ __launch_bounds__(256) void k_el(
    const ushort_t* __restrict__ proj,   // [nsrc,128] bf16
    const float*    __restrict__ al,     // [128]
    const float*    __restrict__ ar,     // [128]
    float*          __restrict__ el,     // [nsrc,4]
    float*          __restrict__ er,     // [ndst,4]
    int nsrc, int ndst)
{
    int wid  = (int)((blockIdx.x * blockDim.x + threadIdx.x) >> 6);
    if (wid >= nsrc) return;
    int l  = threadIdx.x & 63;
    int f0 = 2 * l;

    us2 v = *(const us2*)&proj[(size_t)wid * DIN + f0];
    float v0 = bf2f(v[0]), v1 = bf2f(v[1]);
    float pl = v0 * al[f0] + v1 * al[f0 + 1];
    float pr = v0 * ar[f0] + v1 * ar[f0 + 1];
    #pragma unroll
    for (int m = 1; m < 16; m <<= 1) {
        pl += __shfl_xor(pl, m);
        pr += __shfl_xor(pr, m);
    }
    if ((l & 15) == 0) {
        el[wid * 4 + (l >> 4)] = pl;
        if (wid < ndst) er[wid * 4 + (l >> 4)] = pr;
    }
}

// -------------------------------------------------------------------------
// K4: edge softmax + weighted aggregate. One wave per dst node.
// Stage 1 (lane = k*4+h): e = leaky(el[j_k,h] + er[i,h]); softmax over k.
// Stage 2 (lane = feature/2): acc2 += a_k * proj[j_k, 2l..2l+1], coalesced.
// -------------------------------------------------------------------------
__global__ __launch_bounds__(256) void k_agg(
    const ushort_t* __restrict__ proj,   // [nsrc,128] bf16
    const int*      __restrict__ idx,    // [ndst,16] (relation slice)
    const float*    __restrict__ el,     // [nsrc,4]
    const float*    __restrict__ er,     // [ndst,4]
    const float*    __restrict__ br,     // [128]
    float*          __restrict__ accg,   // [ndst,128] f32, += over relations
    int ndst)
{
    int wid  = (int)((blockIdx.x * blockDim.x + threadIdx.x) >> 6);
    if (wid >= ndst) return;
    int l = threadIdx.x & 63;

    int jv = idx[(size_t)wid * KNB + (l & 15)];

    // ---- stage 1: attention coefficients (lane = k*4 + h)
    int   jk = __shfl(jv, l >> 2);
    float e  = el[(size_t)jk * 4 + (l & 3)] + er[(size_t)wid * 4 + (l & 3)];
    e = e > 0.f ? e : 0.2f * e;           // leaky_relu
    float mx = e;
    #pragma unroll
    for (int m = 4; m < 64; m <<= 1) mx = fmaxf(mx, __shfl_xor(mx, m));
    float p = __expf(e - mx);
    float s = p;
    #pragma unroll
    for (int m = 4; m < 64; m <<= 1) s += __shfl_xor(s, m);
    float a = p / s;

    // ---- stage 2: weighted sum (lane owns features 2l, 2l+1; head = l>>4)
    float ax = 0.f, ay = 0.f;
    #pragma unroll
    for (int k = 0; k < KNB; ++k) {
        int   j  = __shfl(jv, k);
        float ak = __shfl(a, k * 4 + (l >> 4));
        us2   v  = *(const us2*)&proj[(size_t)j * DIN + 2 * l];
        ax = fmaf(ak, bf2f(v[0]), ax);
        ay = fmaf(ak, bf2f(v[1]), ay);
    }

    float* ap = accg + (size_t)wid * DIN + 2 * l;
    ap[0] += ax + br[2 * l];
    ap[1] += ay + br[2 * l + 1];
}

// -------------------------------------------------------------------------
// K5: out[t] = relu(acc[root[t/128]][t%128] / R)
// -------------------------------------------------------------------------
__global__ __launch_bounds__(256) void k_root(
    const float* __restrict__ acc, const int* __restrict__ root,
    float* __restrict__ out, int n)
{
    int t = blockIdx.x * blockDim.x + threadIdx.x;
    if (t < n) {
        float x = acc[(size_t)root[t >> 7] * DIN + (t & 127)];
        out[t] = fmaxf(x * (1.f / (float)R), 0.f);
    }
}

// -------------------------------------------------------------------------
extern "C" void kernel_launch(void* const* d_in, const int* in_sizes, int n_in,
                              void* d_out, int out_size, void* d_ws, size_t ws_size,
                              hipStream_t stream)
{
    const float* emb    = (const float*)d_in[0];
    const float* freq   = (const float*)d_in[1];
    const float* phase  = (const float*)d_in[2];
    const float* gamma0 = (const float*)d_in[3];
    const float* beta0  = (const float*)d_in[4];
    const float* W0     = (const float*)d_in[5];
    const float* al0    = (const float*)d_in[6];
    const float* ar0    = (const float*)d_in[7];
    const float* b0     = (const float*)d_in[8];
    const float* gamma1 = (const float*)d_in[9];
    const float* beta1  = (const float*)d_in[10];
    const float* W1     = (const float*)d_in[11];
    const float* al1    = (const float*)d_in[12];
    const float* ar1    = (const float*)d_in[13];
    const float* b1     = (const float*)d_in[14];
    const int* src_ids0 = (const int*)d_in[15];
    const int* src_idx0 = (const int*)d_in[16];
    const int* src_ids1 = (const int*)d_in[17];
    const int* src_idx1 = (const int*)d_in[18];
    const int* root     = (const int*)d_in[19];
    const int* ts       = (const int*)d_in[20];
    float* out = (float*)d_out;

    // workspace layout (~96.3 MB)
    ushort_t* hn   = (ushort_t*)d_ws;                       // [N0,160] bf16
    ushort_t* proj = hn   + (size_t)N0 * DINT;              // [N0,128] bf16
    float*    acc  = (float*)(proj + (size_t)N0 * DIN);     // [N1,128] f32
    float*    el   = acc  + (size_t)N1 * DIN;               // [N0,4]   f32
    float*    er   = el   + (size_t)N0 * 4;                 // [N1,4]   f32
    ushort_t* wt0  = (ushort_t*)(er + (size_t)N1 * 4);      // [R,128,160] bf16
    ushort_t* wt1  = wt0 + (size_t)R * DIN * DINT;          // [R,128,160] bf16

    const int WTOT = R * DINT * DIN;

    // ---------------- layer 0 ----------------
    k_wcast<<<(WTOT + 255) / 256, 256, 0, stream>>>(W0, wt0, WTOT);
    hipMemsetAsync(acc, 0, (size_t)N1 * DIN * sizeof(float), stream);
    k_prep<<<N0 / 4, 256, 0, stream>>>(emb, src_ids0, ts, freq, phase,
                                       gamma0, beta0, hn, N0, 1);
    for (int r = 0; r < R; ++r) {
        k_gemm<<<N0 / 128, 256, 0, stream>>>(hn, wt0 + (size_t)r * DIN * DINT, proj, N0);
        k_el<<<N0 / 4, 256, 0, stream>>>(proj, al0 + r * 128, ar0 + r * 128,
                                         el, er, N0, N1);
        k_agg<<<N1 / 4, 256, 0, stream>>>(proj,
                                          src_idx0 + (size_t)r * N1 * KNB,
                                          el, er, b0 + r * 128, acc, N1);
    }

    // ---------------- layer 1 ----------------
    k_wcast<<<(WTOT + 255) / 256, 256, 0, stream>>>(W1, wt1, WTOT);
    // prep reads layer-0 acc (applies relu(x/R) inline) BEFORE acc is reused
    k_prep<<<N1 / 4, 256, 0, stream>>>(acc, src_ids1, ts, freq, phase,
                                       gamma1, beta1, hn, N1, 0);
    hipMemsetAsync(acc, 0, (size_t)N2 * DIN * sizeof(float), stream);
    for (int r = 0; r < R; ++r) {
        k_gemm<<<N1 / 128, 256, 0, stream>>>(hn, wt1 + (size_t)r * DIN * DINT, proj, N1);
        k_el<<<N1 / 4, 256, 0, stream>>>(proj, al1 + r * 128, ar1 + r * 128,
                                         el, er, N1, N2);
        k_agg<<<N2 / 4, 256, 0, stream>>>(proj,
                                          src_idx1 + (size_t)r * N2 * KNB,
                                          el, er, b1 + r * 128, acc, N2);
    }

    // ---------------- root gather (+ relu(x/R)) ----------------
    k_root<<<(N2 * DIN) / 256, 256, 0, stream>>>(acc, root, out, N2 * DIN);
}

// Round 6
// 1449.094 us; speedup vs baseline: 2.3181x; 1.1422x over previous
//
#include <hip/hip_runtime.h>
#include <hip/hip_bf16.h>

// Problem constants (from reference)
#define NUME 100000
constexpr int H      = 4;
constexpr int DH     = 32;
constexpr int KNB    = 16;     // neighbors per dst
constexpr int R      = 17;     // relations
constexpr int DIN    = 128;
constexpr int DT     = 32;
constexpr int DINT   = 160;    // DIN + DT
constexpr int N0     = 131072;
constexpr int N1     = 32768;
constexpr int N2     = 4096;
constexpr float LN_EPS = 1e-5f;

typedef unsigned short ushort_t;
typedef ushort_t us2 __attribute__((ext_vector_type(2)));
typedef ushort_t us8 __attribute__((ext_vector_type(8)));
typedef short    s8v __attribute__((ext_vector_type(8)));
typedef float    f32x4 __attribute__((ext_vector_type(4)));

__device__ __forceinline__ float bf2f(ushort_t u) {
    return __uint_as_float(((unsigned int)u) << 16);
}
__device__ __forceinline__ ushort_t f2bf(float f) {   // round-to-nearest-even
    unsigned int x = __float_as_uint(f);
    unsigned int r = x + 0x7fffu + ((x >> 16) & 1u);
    return (ushort_t)(r >> 16);
}

// -------------------------------------------------------------------------
// K0: W [R][160][128] f32  ->  wt [R][128][160] bf16 (transposed per rel)
// -------------------------------------------------------------------------
__global__ __launch_bounds__(256) void k_wcast(
    const float* __restrict__ W, ushort_t* __restrict__ wt, int total)
{
    int t = blockIdx.x * blockDim.x + threadIdx.x;
    if (t >= total) return;
    int r   = t / (DINT * DIN);
    int rem = t % (DINT * DIN);
    int k   = rem >> 7;            // 0..159
    int n   = rem & 127;           // 0..127
    wt[(size_t)r * DIN * DINT + (size_t)n * DINT + k] = f2bf(W[t]);
}

// -------------------------------------------------------------------------
// K1: [optional relu(x/R)] + time-enc + concat + LayerNorm. One wave per row.
// mode=1: row = emb[ids[n] % NUME]   (layer 0)
// mode=0: row = relu(srcf[n]/R)      (layer 1: srcf = layer-0 acc)
// -------------------------------------------------------------------------
__global__ __launch_bounds__(256) void k_prep(
    const float* __restrict__ srcf,
    const int*   __restrict__ ids,
    const int*   __restrict__ ts_ptr,
    const float* __restrict__ freq,
    const float* __restrict__ phase,
    const float* __restrict__ gamma,
    const float* __restrict__ beta,
    ushort_t*    __restrict__ hn,
    int n_rows, int mode)
{
    int wid  = (int)((blockIdx.x * blockDim.x + threadIdx.x) >> 6);
    int lane = threadIdx.x & 63;
    if (wid >= n_rows) return;

    int id = ids[wid];
    const float* row = (mode == 1)
        ? (srcf + (size_t)(id % NUME) * DIN)
        : (srcf + (size_t)wid * DIN);

    float x0 = row[lane];
    float x1 = row[lane + 64];
    if (mode == 0) {
        x0 = fmaxf(x0 * (1.f / (float)R), 0.f);
        x1 = fmaxf(x1 * (1.f / (float)R), 0.f);
    }

    int   ts = ts_ptr[0];
    float t  = (float)(ts - id / NUME);
    float p  = 0.f;
    if (lane < DT) p = cosf(t * freq[lane] + phase[lane]);

    float s  = x0 + x1 + p;
    float sq = x0*x0 + x1*x1 + p*p;
    #pragma unroll
    for (int m = 1; m < 64; m <<= 1) {
        s  += __shfl_xor(s,  m);
        sq += __shfl_xor(sq, m);
    }
    float mu   = s / (float)DINT;
    float var  = sq / (float)DINT - mu * mu;
    float rstd = rsqrtf(var + LN_EPS);

    size_t base = (size_t)wid * DINT;
    hn[base + lane]      = f2bf((x0 - mu) * rstd * gamma[lane]      + beta[lane]);
    hn[base + 64 + lane] = f2bf((x1 - mu) * rstd * gamma[64 + lane] + beta[64 + lane]);
    if (lane < DT)
        hn[base + 128 + lane] = f2bf((p - mu) * rstd * gamma[128 + lane] + beta[128 + lane]);
}

// -------------------------------------------------------------------------
// K2: MFMA GEMM + fused attention-dot epilogue.
// proj[M,128](bf16) = hn[M,160](bf16) @ wt^T      (wt slice is [128][160])
// el[m][h] = proj[m, 32h:32h+32] . al[32h:+32]    (h = 0..3), er likewise
// 256 thr = 4 waves (2x2), tile 128x128, K chunks of 32, 16x16x32 bf16 MFMA.
// C/D frag: col = lane&15, row = (lane>>4)*4 + q   [m89-verified]
// Head h spans 32 cols = 2 j-tiles, entirely within one wc half -> per-wave
// multi-value butterfly (5 shfl per (i,q)) reduces the 16-lane col dim.
// -------------------------------------------------------------------------
__global__ __launch_bounds__(256) void k_gemm(
    const ushort_t* __restrict__ A,    // [M,160] bf16
    const ushort_t* __restrict__ Bt,   // [128,160] bf16 (relation slice of wt)
    const float*    __restrict__ al,   // [128] f32 (relation slice)
    const float*    __restrict__ ar,   // [128]
    ushort_t*       __restrict__ C,    // [M,128] bf16
    float*          __restrict__ el,   // [M,4]
    float*          __restrict__ er,   // [ndst,4]
    int ndst)
{
    __shared__ ushort_t As[128][40];   // padded: stride 80 B (2-way bank max)
    __shared__ ushort_t Bs[128][40];

    int tid  = threadIdx.x;
    int lane = tid & 63;
    int wave = tid >> 6;
    int wr   = wave >> 1;              // 0..1: row half
    int wc   = wave & 1;               // 0..1: col half
    int row0 = blockIdx.x * 128;

    f32x4 acc[4][4];
    #pragma unroll
    for (int i = 0; i < 4; ++i)
        #pragma unroll
        for (int j = 0; j < 4; ++j) acc[i][j] = (f32x4){0.f, 0.f, 0.f, 0.f};

    for (int kc = 0; kc < DINT; kc += 32) {
        #pragma unroll
        for (int j = 0; j < 2; ++j) {
            int f  = tid + j * 256;          // 0..511
            int m  = f >> 2;                 // 0..127
            int ko = (f & 3) * 8;            // 0,8,16,24
            *(us8*)&As[m][ko] = *(const us8*)&A [(size_t)(row0 + m) * DINT + kc + ko];
            *(us8*)&Bs[m][ko] = *(const us8*)&Bt[(size_t)m          * DINT + kc + ko];
        }
        __syncthreads();

        s8v af[4], bfr[4];
        #pragma unroll
        for (int i = 0; i < 4; ++i)
            af[i] = *(const s8v*)&As[wr*64 + i*16 + (lane & 15)][(lane >> 4) * 8];
        #pragma unroll
        for (int j = 0; j < 4; ++j)
            bfr[j] = *(const s8v*)&Bs[wc*64 + j*16 + (lane & 15)][(lane >> 4) * 8];

        #pragma unroll
        for (int i = 0; i < 4; ++i)
            #pragma unroll
            for (int j = 0; j < 4; ++j)
                acc[i][j] = __builtin_amdgcn_mfma_f32_16x16x32_bf16(
                                af[i], bfr[j], acc[i][j], 0, 0, 0);
        __syncthreads();
    }

    // ---- C write-out
    #pragma unroll
    for (int i = 0; i < 4; ++i) {
        #pragma unroll
        for (int j = 0; j < 4; ++j) {
            int col  = wc*64 + j*16 + (lane & 15);
            int rowb = row0 + wr*64 + i*16 + ((lane >> 4) << 2);
            #pragma unroll
            for (int q = 0; q < 4; ++q)
                C[(size_t)(rowb + q) * DIN + col] = f2bf(acc[i][j][q]);
        }
    }

    // ---- fused el/er epilogue
    float alv[4], arv[4];
    #pragma unroll
    for (int j = 0; j < 4; ++j) {
        int c = wc*64 + j*16 + (lane & 15);
        alv[j] = al[c];
        arv[j] = ar[c];
    }
    int b0 = lane & 1;
    int b1 = (lane >> 1) & 1;
    #pragma unroll
    for (int i = 0; i < 4; ++i) {
        #pragma unroll
        for (int q = 0; q < 4; ++q) {
            // head (2wc+0) partial = j 0,1 ; head (2wc+1) partial = j 2,3
            float pl0 = acc[i][0][q]*alv[0] + acc[i][1][q]*alv[1];
            float pl1 = acc[i][2][q]*alv[2] + acc[i][3][q]*alv[3];
            float pr0 = acc[i][0][q]*arv[0] + acc[i][1][q]*arv[1];
            float pr1 = acc[i][2][q]*arv[2] + acc[i][3][q]*arv[3];
            // multi-value butterfly over lane bits 0..3 (16-lane col dim)
            float t;
            t = __shfl_xor(b0 ? pl0 : pl1, 1);
            float vA = (b0 ? pl1 : pl0) + t;          // pl class, idx=b0
            t = __shfl_xor(b0 ? pr0 : pr1, 1);
            float vB = (b0 ? pr1 : pr0) + t;          // pr class, idx=b0
            t = __shfl_xor(b1 ? vA : vB, 2);
            float vC = (b1 ? vB : vA) + t;            // b1=0 -> pl, b1=1 -> pr
            vC += __shfl_xor(vC, 4);
            vC += __shfl_xor(vC, 8);
            if ((lane & 12) == 0) {
                int row = row0 + wr*64 + i*16 + ((lane >> 4) << 2) + q;
                int h   = 2*wc + b0;
                if (!b1) {
                    el[(size_t)row * 4 + h] = vC;
                } else if (row < ndst) {
                    er[(size_t)row * 4 + h] = vC;
                }
            }
        }
    }
}

// -------------------------------------------------------------------------
// K3: edge softmax + weighted aggregate. One wave per dst node.
// Stage 1 (lane = k*4+h): e = leaky(el[j_k,h] + er[i,h]); softmax over k.
// Stage 2 (lane = rsub*16+fg): 4 neighbor rows in flight, us8 loads,
//          2-round cross-rsub reduce, 512B coalesced RMW by lanes 0..15.
// -------------------------------------------------------------------------
__global__ __launch_bounds__(256) void k_agg(
    const ushort_t* __restrict__ proj,   // [nsrc,128] bf16
    const int*      __restrict__ idx,    // [ndst,16] (relation slice)
    const float*    __restrict__ el,     // [nsrc,4]
    const float*    __restrict__ er,     // [ndst,4]
    const float*    __restrict__ br,     // [128]
    float*          __restrict__ accg,   // [ndst,128] f32, += over relations
    int ndst)
{
    int wid  = (int)((blockIdx.x * blockDim.x + threadIdx.x) >> 6);
    if (wid >= ndst) return;
    int l = threadIdx.x & 63;

    int jv = idx[(size_t)wid * KNB + (l & 15)];

    // ---- stage 1: attention coefficients (lane = k*4 + h)
    int   jk = __shfl(jv, l >> 2);
    float e  = el[(size_t)jk * 4 + (l & 3)] + er[(size_t)wid * 4 + (l & 3)];
    e = e > 0.f ? e : 0.2f * e;           // leaky_relu
    float mx = e;
    #pragma unroll
    for (int m = 4; m < 64; m <<= 1) mx = fmaxf(mx, __shfl_xor(mx, m));
    float p = __expf(e - mx);
    float s = p;
    #pragma unroll
    for (int m = 4; m < 64; m <<= 1) s += __shfl_xor(s, m);
    float a = p / s;

    // ---- stage 2: weighted sum, 4 rows at a time
    int rsub = l >> 4;          // 0..3
    int fg   = l & 15;          // feature group: 8 feats at fg*8
    float vacc[8];
    #pragma unroll
    for (int t = 0; t < 8; ++t) vacc[t] = 0.f;

    #pragma unroll
    for (int kk = 0; kk < 4; ++kk) {
        int   j  = __shfl(jv, 4*kk + rsub);
        float ak = __shfl(a, 16*kk + 4*rsub + (fg >> 2));
        us8   v  = *(const us8*)&proj[(size_t)j * DIN + fg * 8];
        #pragma unroll
        for (int t = 0; t < 8; ++t) vacc[t] = fmaf(ak, bf2f(v[t]), vacc[t]);
    }
    #pragma unroll
    for (int t = 0; t < 8; ++t) {
        vacc[t] += __shfl_xor(vacc[t], 16);
        vacc[t] += __shfl_xor(vacc[t], 32);
    }
    if (l < 16) {
        float* ap = accg + (size_t)wid * DIN + l * 8;
        #pragma unroll
        for (int t = 0; t < 8; ++t) ap[t] += vacc[t] + br[l * 8 + t];
    }
}

// -------------------------------------------------------------------------
// K5: out[t] = relu(acc[root[t/128]][t%128] / R)
// -------------------------------------------------------------------------
__global__ __launch_bounds__(256) void k_root(
    const float* __restrict__ acc, const int* __restrict__ root,
    float* __restrict__ out, int n)
{
    int t = blockIdx.x * blockDim.x + threadIdx.x;
    if (t < n) {
        float x = acc[(size_t)root[t >> 7] * DIN + (t & 127)];
        out[t] = fmaxf(x * (1.f / (float)R), 0.f);
    }
}

// -------------------------------------------------------------------------
extern "C" void kernel_launch(void* const* d_in, const int* in_sizes, int n_in,
                              void* d_out, int out_size, void* d_ws, size_t ws_size,
                              hipStream_t stream)
{
    const float* emb    = (const float*)d_in[0];
    const float* freq   = (const float*)d_in[1];
    const float* phase  = (const float*)d_in[2];
    const float* gamma0 = (const float*)d_in[3];
    const float* beta0  = (const float*)d_in[4];
    const float* W0     = (const float*)d_in[5];
    const float* al0    = (const float*)d_in[6];
    const float* ar0    = (const float*)d_in[7];
    const float* b0     = (const float*)d_in[8];
    const float* gamma1 = (const float*)d_in[9];
    const float* beta1  = (const float*)d_in[10];
    const float* W1     = (const float*)d_in[11];
    const float* al1    = (const float*)d_in[12];
    const float* ar1    = (const float*)d_in[13];
    const float* b1     = (const float*)d_in[14];
    const int* src_ids0 = (const int*)d_in[15];
    const int* src_idx0 = (const int*)d_in[16];
    const int* src_ids1 = (const int*)d_in[17];
    const int* src_idx1 = (const int*)d_in[18];
    const int* root     = (const int*)d_in[19];
    const int* ts       = (const int*)d_in[20];
    float* out = (float*)d_out;

    // workspace layout (~96.3 MB)
    ushort_t* hn   = (ushort_t*)d_ws;                       // [N0,160] bf16
    ushort_t* proj = hn   + (size_t)N0 * DINT;              // [N0,128] bf16
    float*    acc  = (float*)(proj + (size_t)N0 * DIN);     // [N1,128] f32
    float*    el   = acc  + (size_t)N1 * DIN;               // [N0,4]   f32
    float*    er   = el   + (size_t)N0 * 4;                 // [N1,4]   f32
    ushort_t* wt0  = (ushort_t*)(er + (size_t)N1 * 4);      // [R,128,160] bf16
    ushort_t* wt1  = wt0 + (size_t)R * DIN * DINT;          // [R,128,160] bf16

    const int WTOT = R * DINT * DIN;

    // ---------------- layer 0 ----------------
    k_wcast<<<(WTOT + 255) / 256, 256, 0, stream>>>(W0, wt0, WTOT);
    hipMemsetAsync(acc, 0, (size_t)N1 * DIN * sizeof(float), stream);
    k_prep<<<N0 / 4, 256, 0, stream>>>(emb, src_ids0, ts, freq, phase,
                                       gamma0, beta0, hn, N0, 1);
    for (int r = 0; r < R; ++r) {
        k_gemm<<<N0 / 128, 256, 0, stream>>>(hn, wt0 + (size_t)r * DIN * DINT,
                                             al0 + r * 128, ar0 + r * 128,
                                             proj, el, er, N1);
        k_agg<<<N1 / 4, 256, 0, stream>>>(proj,
                                          src_idx0 + (size_t)r * N1 * KNB,
                                          el, er, b0 + r * 128, acc, N1);
    }

    // ---------------- layer 1 ----------------
    k_wcast<<<(WTOT + 255) / 256, 256, 0, stream>>>(W1, wt1, WTOT);
    // prep reads layer-0 acc (applies relu(x/R) inline) BEFORE acc is reused
    k_prep<<<N1 / 4, 256, 0, stream>>>(acc, src_ids1, ts, freq, phase,
                                       gamma1, beta1, hn, N1, 0);
    hipMemsetAsync(acc, 0, (size_t)N2 * DIN * sizeof(float), stream);
    for (int r = 0; r < R; ++r) {
        k_gemm<<<N1 / 128, 256, 0, stream>>>(hn, wt1 + (size_t)r * DIN * DINT,
                                             al1 + r * 128, ar1 + r * 128,
                                             proj, el, er, N2);
        k_agg<<<N2 / 4, 256, 0, stream>>>(proj,
                                          src_idx1 + (size_t)r * N2 * KNB,
                                          el, er, b1 + r * 128, acc, N2);
    }

    // ---------------- root gather (+ relu(x/R)) ----------------
    k_root<<<(N2 * DIN) / 256, 256, 0, stream>>>(acc, root, out, N2 * DIN);
}

// Round 7
// 1447.340 us; speedup vs baseline: 2.3209x; 1.0012x over previous
//
#include <hip/hip_runtime.h>
#include <hip/hip_bf16.h>

// Problem constants (from reference)
#define NUME 100000
constexpr int H      = 4;
constexpr int DH     = 32;
constexpr int KNB    = 16;     // neighbors per dst
constexpr int R      = 17;     // relations
constexpr int DIN    = 128;
constexpr int DT     = 32;
constexpr int DINT   = 160;    // DIN + DT
constexpr int N0     = 131072;
constexpr int N1     = 32768;
constexpr int N2     = 4096;
constexpr float LN_EPS = 1e-5f;

typedef unsigned short ushort_t;
typedef ushort_t us2 __attribute__((ext_vector_type(2)));
typedef ushort_t us8 __attribute__((ext_vector_type(8)));
typedef short    s8v __attribute__((ext_vector_type(8)));
typedef float    f32x4 __attribute__((ext_vector_type(4)));

__device__ __forceinline__ float bf2f(ushort_t u) {
    return __uint_as_float(((unsigned int)u) << 16);
}
__device__ __forceinline__ ushort_t f2bf(float f) {   // round-to-nearest-even
    unsigned int x = __float_as_uint(f);
    unsigned int r = x + 0x7fffu + ((x >> 16) & 1u);
    return (ushort_t)(r >> 16);
}

// -------------------------------------------------------------------------
// K0: W [R][160][128] f32  ->  wt [R][128][160] bf16 (transposed per rel)
// -------------------------------------------------------------------------
__global__ __launch_bounds__(256) void k_wcast(
    const float* __restrict__ W, ushort_t* __restrict__ wt, int total)
{
    int t = blockIdx.x * blockDim.x + threadIdx.x;
    if (t >= total) return;
    int r   = t / (DINT * DIN);
    int rem = t % (DINT * DIN);
    int k   = rem >> 7;            // 0..159
    int n   = rem & 127;           // 0..127
    wt[(size_t)r * DIN * DINT + (size_t)n * DINT + k] = f2bf(W[t]);
}

// -------------------------------------------------------------------------
// K1: [optional relu(x/R)] + time-enc + concat + LayerNorm. One wave per row.
// mode=1: row = emb[ids[n] % NUME]   (layer 0)
// mode=0: row = relu(srcf[n]/R)      (layer 1: srcf = layer-0 acc)
// -------------------------------------------------------------------------
__global__ __launch_bounds__(256) void k_prep(
    const float* __restrict__ srcf,
    const int*   __restrict__ ids,
    const int*   __restrict__ ts_ptr,
    const float* __restrict__ freq,
    const float* __restrict__ phase,
    const float* __restrict__ gamma,
    const float* __restrict__ beta,
    ushort_t*    __restrict__ hn,
    int n_rows, int mode)
{
    int wid  = (int)((blockIdx.x * blockDim.x + threadIdx.x) >> 6);
    int lane = threadIdx.x & 63;
    if (wid >= n_rows) return;

    int id = ids[wid];
    const float* row = (mode == 1)
        ? (srcf + (size_t)(id % NUME) * DIN)
        : (srcf + (size_t)wid * DIN);

    float x0 = row[lane];
    float x1 = row[lane + 64];
    if (mode == 0) {
        x0 = fmaxf(x0 * (1.f / (float)R), 0.f);
        x1 = fmaxf(x1 * (1.f / (float)R), 0.f);
    }

    int   ts = ts_ptr[0];
    float t  = (float)(ts - id / NUME);
    float p  = 0.f;
    if (lane < DT) p = cosf(t * freq[lane] + phase[lane]);

    float s  = x0 + x1 + p;
    float sq = x0*x0 + x1*x1 + p*p;
    #pragma unroll
    for (int m = 1; m < 64; m <<= 1) {
        s  += __shfl_xor(s,  m);
        sq += __shfl_xor(sq, m);
    }
    float mu   = s / (float)DINT;
    float var  = sq / (float)DINT - mu * mu;
    float rstd = rsqrtf(var + LN_EPS);

    size_t base = (size_t)wid * DINT;
    hn[base + lane]      = f2bf((x0 - mu) * rstd * gamma[lane]      + beta[lane]);
    hn[base + 64 + lane] = f2bf((x1 - mu) * rstd * gamma[64 + lane] + beta[64 + lane]);
    if (lane < DT)
        hn[base + 128 + lane] = f2bf((p - mu) * rstd * gamma[128 + lane] + beta[128 + lane]);
}

// -------------------------------------------------------------------------
// K2: MFMA GEMM + fused attention-dot epilogue (v2: B-resident staging).
// proj[M,128](bf16) = hn[M,160](bf16) @ wt^T      (wt slice is [128][160])
// - Bs staged to LDS once (full K), then hoisted to registers (20 s8v/wave).
// - As double-buffered in kc chunks of 32 -> ONE barrier per kc.
// C/D frag: col = lane&15, row = (lane>>4)*4 + q   [m89-verified]
// el[m][h] = proj[m, 32h:+32] . al ; er likewise (dst rows only).
// -------------------------------------------------------------------------
__global__ __launch_bounds__(256) void k_gemm(
    const ushort_t* __restrict__ A,    // [M,160] bf16
    const ushort_t* __restrict__ Bt,   // [128,160] bf16 (relation slice of wt)
    const float*    __restrict__ al,   // [128] f32 (relation slice)
    const float*    __restrict__ ar,   // [128]
    ushort_t*       __restrict__ C,    // [M,128] bf16
    float*          __restrict__ el,   // [M,4]
    float*          __restrict__ er,   // [ndst,4]
    int ndst)
{
    __shared__ ushort_t Bs[128][168];     // full K=160 + pad (stride 336B = 21*16)
    __shared__ ushort_t As[2][128][40];   // kc chunks of 32 + pad (stride 80B)

    int tid  = threadIdx.x;
    int lane = tid & 63;
    int wave = tid >> 6;
    int wr   = wave >> 1;              // 0..1: row half
    int wc   = wave & 1;               // 0..1: col half
    int row0 = blockIdx.x * 128;

    // ---- prologue: stage full Bs + As chunk 0
    {
        int bm  = tid >> 1;            // 0..127
        int bko = (tid & 1) * 80;      // half-row
        #pragma unroll
        for (int g = 0; g < 10; ++g)
            *(us8*)&Bs[bm][bko + g * 8] =
                *(const us8*)&Bt[(size_t)bm * DINT + bko + g * 8];
        #pragma unroll
        for (int j = 0; j < 2; ++j) {
            int f  = tid + j * 256;    // 0..511
            int m  = f >> 2;
            int ko = (f & 3) * 8;
            *(us8*)&As[0][m][ko] = *(const us8*)&A[(size_t)(row0 + m) * DINT + ko];
        }
    }
    __syncthreads();

    // ---- hoist B fragments to registers: 5 kc x 4 j = 80 VGPR
    s8v breg[5][4];
    #pragma unroll
    for (int kk = 0; kk < 5; ++kk)
        #pragma unroll
        for (int j = 0; j < 4; ++j)
            breg[kk][j] = *(const s8v*)&Bs[wc*64 + j*16 + (lane & 15)]
                                          [kk*32 + (lane >> 4) * 8];

    f32x4 acc[4][4];
    #pragma unroll
    for (int i = 0; i < 4; ++i)
        #pragma unroll
        for (int j = 0; j < 4; ++j) acc[i][j] = (f32x4){0.f, 0.f, 0.f, 0.f};

    // ---- main loop: 5 kc chunks, dbuf As, 1 barrier per chunk
    #pragma unroll
    for (int kc = 0; kc < 5; ++kc) {
        us8 pa[2];
        int m0 = 0, ko0 = 0, m1 = 0, ko1 = 0;
        if (kc < 4) {                  // prefetch next A chunk (global -> reg)
            int f0 = tid;              // 0..255
            m0  = f0 >> 2; ko0 = (f0 & 3) * 8;
            pa[0] = *(const us8*)&A[(size_t)(row0 + m0) * DINT + (kc + 1) * 32 + ko0];
            int f1 = tid + 256;        // 256..511
            m1  = f1 >> 2; ko1 = (f1 & 3) * 8;
            pa[1] = *(const us8*)&A[(size_t)(row0 + m1) * DINT + (kc + 1) * 32 + ko1];
        }

        s8v af[4];
        #pragma unroll
        for (int i = 0; i < 4; ++i)
            af[i] = *(const s8v*)&As[kc & 1][wr*64 + i*16 + (lane & 15)]
                                            [(lane >> 4) * 8];
        #pragma unroll
        for (int i = 0; i < 4; ++i)
            #pragma unroll
            for (int j = 0; j < 4; ++j)
                acc[i][j] = __builtin_amdgcn_mfma_f32_16x16x32_bf16(
                                af[i], breg[kc][j], acc[i][j], 0, 0, 0);

        if (kc < 4) {                  // write prefetched chunk to other buffer
            *(us8*)&As[(kc + 1) & 1][m0][ko0] = pa[0];
            *(us8*)&As[(kc + 1) & 1][m1][ko1] = pa[1];
        }
        __syncthreads();
    }

    // ---- C write-out
    #pragma unroll
    for (int i = 0; i < 4; ++i) {
        #pragma unroll
        for (int j = 0; j < 4; ++j) {
            int col  = wc*64 + j*16 + (lane & 15);
            int rowb = row0 + wr*64 + i*16 + ((lane >> 4) << 2);
            #pragma unroll
            for (int q = 0; q < 4; ++q)
                C[(size_t)(rowb + q) * DIN + col] = f2bf(acc[i][j][q]);
        }
    }

    // ---- fused el/er epilogue
    float alv[4], arv[4];
    #pragma unroll
    for (int j = 0; j < 4; ++j) {
        int c = wc*64 + j*16 + (lane & 15);
        alv[j] = al[c];
        arv[j] = ar[c];
    }
    int b0 = lane & 1;
    int b1 = (lane >> 1) & 1;
    #pragma unroll
    for (int i = 0; i < 4; ++i) {
        #pragma unroll
        for (int q = 0; q < 4; ++q) {
            // head (2wc+0) partial = j 0,1 ; head (2wc+1) partial = j 2,3
            float pl0 = acc[i][0][q]*alv[0] + acc[i][1][q]*alv[1];
            float pl1 = acc[i][2][q]*alv[2] + acc[i][3][q]*alv[3];
            float pr0 = acc[i][0][q]*arv[0] + acc[i][1][q]*arv[1];
            float pr1 = acc[i][2][q]*arv[2] + acc[i][3][q]*arv[3];
            // multi-value butterfly over lane bits 0..3 (16-lane col dim)
            float t;
            t = __shfl_xor(b0 ? pl0 : pl1, 1);
            float vA = (b0 ? pl1 : pl0) + t;          // pl class, idx=b0
            t = __shfl_xor(b0 ? pr0 : pr1, 1);
            float vB = (b0 ? pr1 : pr0) + t;          // pr class, idx=b0
            t = __shfl_xor(b1 ? vA : vB, 2);
            float vC = (b1 ? vB : vA) + t;            // b1=0 -> pl, b1=1 -> pr
            vC += __shfl_xor(vC, 4);
            vC += __shfl_xor(vC, 8);
            if ((lane & 12) == 0) {
                int row = row0 + wr*64 + i*16 + ((lane >> 4) << 2) + q;
                int h   = 2*wc + b0;
                if (!b1) {
                    el[(size_t)row * 4 + h] = vC;
                } else if (row < ndst) {
                    er[(size_t)row * 4 + h] = vC;
                }
            }
        }
    }
}

// -------------------------------------------------------------------------
// K3: edge softmax + weighted aggregate. One wave per dst node.
// Stage 1 (lane = k*4+h): e = leaky(el[j_k,h] + er[i,h]); softmax over k.
// Stage 2 (lane = rsub*16+fg): 4 neighbor rows in flight, us8 loads,
//          2-round cross-rsub reduce, 512B coalesced RMW by lanes 0..15.
// -------------------------------------------------------------------------
__global__ __launch_bounds__(256) void k_agg(
    const ushort_t* __restrict__ proj,   // [nsrc,128] bf16
    const int*      __restrict__ idx,    // [ndst,16] (relation slice)
    const float*    __restrict__ el,     // [nsrc,4]
    const float*    __restrict__ er,     // [ndst,4]
    const float*    __restrict__ br,     // [128]
    float*          __restrict__ accg,   // [ndst,128] f32, += over relations
    int ndst)
{
    int wid  = (int)((blockIdx.x * blockDim.x + threadIdx.x) >> 6);
    if (wid >= ndst) return;
    int l = threadIdx.x & 63;

    int jv = idx[(size_t)wid * KNB + (l & 15)];

    // ---- stage 1: attention coefficients (lane = k*4 + h)
    int   jk = __shfl(jv, l >> 2);
    float e  = el[(size_t)jk * 4 + (l & 3)] + er[(size_t)wid * 4 + (l & 3)];
    e = e > 0.f ? e : 0.2f * e;           // leaky_relu
    float mx = e;
    #pragma unroll
    for (int m = 4; m < 64; m <<= 1) mx = fmaxf(mx, __shfl_xor(mx, m));
    float p = __expf(e - mx);
    float s = p;
    #pragma unroll
    for (int m = 4; m < 64; m <<= 1) s += __shfl_xor(s, m);
    float a = p / s;

    // ---- stage 2: weighted sum, 4 rows at a time
    int rsub = l >> 4;          // 0..3
    int fg   = l & 15;          // feature group: 8 feats at fg*8
    float vacc[8];
    #pragma unroll
    for (int t = 0; t < 8; ++t) vacc[t] = 0.f;

    #pragma unroll
    for (int kk = 0; kk < 4; ++kk) {
        int   j  = __shfl(jv, 4*kk + rsub);
        float ak = __shfl(a, 16*kk + 4*rsub + (fg >> 2));
        us8   v  = *(const us8*)&proj[(size_t)j * DIN + fg * 8];
        #pragma unroll
        for (int t = 0; t < 8; ++t) vacc[t] = fmaf(ak, bf2f(v[t]), vacc[t]);
    }
    #pragma unroll
    for (int t = 0; t < 8; ++t) {
        vacc[t] += __shfl_xor(vacc[t], 16);
        vacc[t] += __shfl_xor(vacc[t], 32);
    }
    if (l < 16) {
        float* ap = accg + (size_t)wid * DIN + l * 8;
        #pragma unroll
        for (int t = 0; t < 8; ++t) ap[t] += vacc[t] + br[l * 8 + t];
    }
}

// -------------------------------------------------------------------------
// K5: out[t] = relu(acc[root[t/128]][t%128] / R)
// -------------------------------------------------------------------------
__global__ __launch_bounds__(256) void k_root(
    const float* __restrict__ acc, const int* __restrict__ root,
    float* __restrict__ out, int n)
{
    int t = blockIdx.x * blockDim.x + threadIdx.x;
    if (t < n) {
        float x = acc[(size_t)root[t >> 7] * DIN + (t & 127)];
        out[t] = fmaxf(x * (1.f / (float)R), 0.f);
    }
}

// -------------------------------------------------------------------------
extern "C" void kernel_launch(void* const* d_in, const int* in_sizes, int n_in,
                              void* d_out, int out_size, void* d_ws, size_t ws_size,
                              hipStream_t stream)
{
    const float* emb    = (const float*)d_in[0];
    const float* freq   = (const float*)d_in[1];
    const float* phase  = (const float*)d_in[2];
    const float* gamma0 = (const float*)d_in[3];
    const float* beta0  = (const float*)d_in[4];
    const float* W0     = (const float*)d_in[5];
    const float* al0    = (const float*)d_in[6];
    const float* ar0    = (const float*)d_in[7];
    const float* b0     = (const float*)d_in[8];
    const float* gamma1 = (const float*)d_in[9];
    const float* beta1  = (const float*)d_in[10];
    const float* W1     = (const float*)d_in[11];
    const float* al1    = (const float*)d_in[12];
    const float* ar1    = (const float*)d_in[13];
    const float* b1     = (const float*)d_in[14];
    const int* src_ids0 = (const int*)d_in[15];
    const int* src_idx0 = (const int*)d_in[16];
    const int* src_ids1 = (const int*)d_in[17];
    const int* src_idx1 = (const int*)d_in[18];
    const int* root     = (const int*)d_in[19];
    const int* ts       = (const int*)d_in[20];
    float* out = (float*)d_out;

    // workspace layout (~122.6 MB, proven by rounds 5/6)
    ushort_t* hn   = (ushort_t*)d_ws;                       // [N0,160] bf16
    ushort_t* proj = hn   + (size_t)N0 * DINT;              // [N0,128] bf16
    float*    acc  = (float*)(proj + (size_t)N0 * DIN);     // [N1,128] f32
    float*    el   = acc  + (size_t)N1 * DIN;               // [N0,4]   f32
    float*    er   = el   + (size_t)N0 * 4;                 // [N1,4]   f32
    ushort_t* wt0  = (ushort_t*)(er + (size_t)N1 * 4);      // [R,128,160] bf16
    ushort_t* wt1  = wt0 + (size_t)R * DIN * DINT;          // [R,128,160] bf16

    const int WTOT = R * DINT * DIN;

    // ---------------- layer 0 ----------------
    k_wcast<<<(WTOT + 255) / 256, 256, 0, stream>>>(W0, wt0, WTOT);
    hipMemsetAsync(acc, 0, (size_t)N1 * DIN * sizeof(float), stream);
    k_prep<<<N0 / 4, 256, 0, stream>>>(emb, src_ids0, ts, freq, phase,
                                       gamma0, beta0, hn, N0, 1);
    for (int r = 0; r < R; ++r) {
        k_gemm<<<N0 / 128, 256, 0, stream>>>(hn, wt0 + (size_t)r * DIN * DINT,
                                             al0 + r * 128, ar0 + r * 128,
                                             proj, el, er, N1);
        k_agg<<<N1 / 4, 256, 0, stream>>>(proj,
                                          src_idx0 + (size_t)r * N1 * KNB,
                                          el, er, b0 + r * 128, acc, N1);
    }

    // ---------------- layer 1 ----------------
    k_wcast<<<(WTOT + 255) / 256, 256, 0, stream>>>(W1, wt1, WTOT);
    // prep reads layer-0 acc (applies relu(x/R) inline) BEFORE acc is reused
    k_prep<<<N1 / 4, 256, 0, stream>>>(acc, src_ids1, ts, freq, phase,
                                       gamma1, beta1, hn, N1, 0);
    hipMemsetAsync(acc, 0, (size_t)N2 * DIN * sizeof(float), stream);
    for (int r = 0; r < R; ++r) {
        k_gemm<<<N1 / 128, 256, 0, stream>>>(hn, wt1 + (size_t)r * DIN * DINT,
                                             al1 + r * 128, ar1 + r * 128,
                                             proj, el, er, N2);
        k_agg<<<N2 / 4, 256, 0, stream>>>(proj,
                                          src_idx1 + (size_t)r * N2 * KNB,
                                          el, er, b1 + r * 128, acc, N2);
    }

    // ---------------- root gather (+ relu(x/R)) ----------------
    k_root<<<(N2 * DIN) / 256, 256, 0, stream>>>(acc, root, out, N2 * DIN);
}

// Round 8
// 1207.619 us; speedup vs baseline: 2.7816x; 1.1985x over previous
//
#include <hip/hip_runtime.h>
#include <hip/hip_bf16.h>

// Problem constants (from reference)
#define NUME 100000
constexpr int H      = 4;
constexpr int DH     = 32;
constexpr int KNB    = 16;     // neighbors per dst
constexpr int R      = 17;     // relations
constexpr int DIN    = 128;
constexpr int DT     = 32;
constexpr int DINT   = 160;    // DIN + DT
constexpr int N0     = 131072;
constexpr int N1     = 32768;
constexpr int N2     = 4096;
constexpr float LN_EPS = 1e-5f;

typedef unsigned short ushort_t;
typedef ushort_t us4 __attribute__((ext_vector_type(4)));
typedef ushort_t us8 __attribute__((ext_vector_type(8)));
typedef short    s8v __attribute__((ext_vector_type(8)));
typedef float    f32x4 __attribute__((ext_vector_type(4)));

__device__ __forceinline__ float bf2f(ushort_t u) {
    return __uint_as_float(((unsigned int)u) << 16);
}
__device__ __forceinline__ ushort_t f2bf(float f) {   // round-to-nearest-even
    unsigned int x = __float_as_uint(f);
    unsigned int r = x + 0x7fffu + ((x >> 16) & 1u);
    return (ushort_t)(r >> 16);
}

// -------------------------------------------------------------------------
// K0: W [R][160][128] f32  ->  wt [R][128][160] bf16 (transposed per rel)
// -------------------------------------------------------------------------
__global__ __launch_bounds__(256) void k_wcast(
    const float* __restrict__ W, ushort_t* __restrict__ wt, int total)
{
    int t = blockIdx.x * blockDim.x + threadIdx.x;
    if (t >= total) return;
    int r   = t / (DINT * DIN);
    int rem = t % (DINT * DIN);
    int k   = rem >> 7;            // 0..159
    int n   = rem & 127;           // 0..127
    wt[(size_t)r * DIN * DINT + (size_t)n * DINT + k] = f2bf(W[t]);
}

// -------------------------------------------------------------------------
// K0b: bsum0[c] = sum_r b0[r][c], bsum1[c] = sum_r b1[r][c]  (1 block)
// -------------------------------------------------------------------------
__global__ __launch_bounds__(256) void k_bsum(
    const float* __restrict__ b0, const float* __restrict__ b1,
    float* __restrict__ bsum01)
{
    int t = threadIdx.x;                 // 0..255
    const float* b = (t < 128) ? b0 : b1;
    int c = t & 127;
    float s = 0.f;
    #pragma unroll
    for (int r = 0; r < R; ++r) s += b[r * 128 + c];
    bsum01[t] = s;
}

// -------------------------------------------------------------------------
// K1 v2: [optional relu((x+bsum)/R)] + time-enc + concat + LayerNorm.
// One wave = 2 rows (32 lanes each), float4 loads, 5-round butterfly.
// mode=1: row = emb[ids[n] % NUME]   (layer 0)
// mode=0: row = relu((srcf[n]+bsum)/R)  (layer 1)
// -------------------------------------------------------------------------
__global__ __launch_bounds__(256) void k_prep(
    const float* __restrict__ srcf,
    const int*   __restrict__ ids,
    const int*   __restrict__ ts_ptr,
    const float* __restrict__ freq,
    const float* __restrict__ phase,
    const float* __restrict__ gamma,
    const float* __restrict__ beta,
    const float* __restrict__ bsum,      // [128], used in mode 0
    ushort_t*    __restrict__ hn,
    int n_rows, int mode)
{
    int wv   = (int)((blockIdx.x * blockDim.x + threadIdx.x) >> 6);
    int lane = threadIdx.x & 63;
    int half = lane >> 5;                // 0,1 : which row of the pair
    int l5   = lane & 31;                // 0..31
    int row  = wv * 2 + half;
    if (row >= n_rows) return;

    int id = ids[row];
    const float* rp = (mode == 1)
        ? (srcf + (size_t)(id % NUME) * DIN)
        : (srcf + (size_t)row * DIN);

    float4 x = *(const float4*)&rp[l5 * 4];
    if (mode == 0) {
        const float4 bs = *(const float4*)&bsum[l5 * 4];
        x.x = fmaxf((x.x + bs.x) * (1.f / (float)R), 0.f);
        x.y = fmaxf((x.y + bs.y) * (1.f / (float)R), 0.f);
        x.z = fmaxf((x.z + bs.z) * (1.f / (float)R), 0.f);
        x.w = fmaxf((x.w + bs.w) * (1.f / (float)R), 0.f);
    }

    int   ts = ts_ptr[0];
    float t  = (float)(ts - id / NUME);
    float p  = cosf(t * freq[l5] + phase[l5]);   // one phi element per lane

    float s  = x.x + x.y + x.z + x.w + p;
    float sq = x.x*x.x + x.y*x.y + x.z*x.z + x.w*x.w + p*p;
    #pragma unroll
    for (int m = 1; m < 32; m <<= 1) {           // stays within the 32-lane half
        s  += __shfl_xor(s,  m);
        sq += __shfl_xor(sq, m);
    }
    float mu   = s / (float)DINT;
    float var  = sq / (float)DINT - mu * mu;
    float rstd = rsqrtf(var + LN_EPS);

    size_t base = (size_t)row * DINT;
    us4 pk;
    pk[0] = f2bf((x.x - mu) * rstd * gamma[l5*4+0] + beta[l5*4+0]);
    pk[1] = f2bf((x.y - mu) * rstd * gamma[l5*4+1] + beta[l5*4+1]);
    pk[2] = f2bf((x.z - mu) * rstd * gamma[l5*4+2] + beta[l5*4+2]);
    pk[3] = f2bf((x.w - mu) * rstd * gamma[l5*4+3] + beta[l5*4+3]);
    *(us4*)&hn[base + l5*4] = pk;
    hn[base + 128 + l5] = f2bf((p - mu) * rstd * gamma[128 + l5] + beta[128 + l5]);
}

// -------------------------------------------------------------------------
// K2: MFMA GEMM + fused attention-dot epilogue (B-resident, dbuf A).
// r = blockIdx.y selects the relation slice (per-r launches use gridDim.y=1
// with pre-offset pointers). C/el/er strided by r.
// -------------------------------------------------------------------------
__global__ __launch_bounds__(256) void k_gemm(
    const ushort_t* __restrict__ A,      // [M,160] bf16
    const ushort_t* __restrict__ BtB,    // [R?,128,160] bf16 base
    const float*    __restrict__ alB,    // [R?,128] base
    const float*    __restrict__ arB,
    ushort_t*       __restrict__ CB,     // [R?,M,128] base
    float*          __restrict__ elB,    // [R?,M,4] base
    float*          __restrict__ erB,    // [R?,ndst,4] base
    int ndst, int M)
{
    __shared__ ushort_t Bs[128][168];     // full K=160 + pad
    __shared__ ushort_t As[2][128][40];   // kc chunks of 32 + pad

    int r = blockIdx.y;
    const ushort_t* Bt = BtB + (size_t)r * DIN * DINT;
    const float*    al = alB + (size_t)r * DIN;
    const float*    ar = arB + (size_t)r * DIN;
    ushort_t*       C  = CB  + (size_t)r * M * DIN;
    float*          el = elB + (size_t)r * M * 4;
    float*          er = erB + (size_t)r * ndst * 4;

    int tid  = threadIdx.x;
    int lane = tid & 63;
    int wave = tid >> 6;
    int wr   = wave >> 1;
    int wc   = wave & 1;
    int row0 = blockIdx.x * 128;

    // ---- prologue: stage full Bs + As chunk 0
    {
        int bm  = tid >> 1;
        int bko = (tid & 1) * 80;
        #pragma unroll
        for (int g = 0; g < 10; ++g)
            *(us8*)&Bs[bm][bko + g * 8] =
                *(const us8*)&Bt[(size_t)bm * DINT + bko + g * 8];
        #pragma unroll
        for (int j = 0; j < 2; ++j) {
            int f  = tid + j * 256;
            int m  = f >> 2;
            int ko = (f & 3) * 8;
            *(us8*)&As[0][m][ko] = *(const us8*)&A[(size_t)(row0 + m) * DINT + ko];
        }
    }
    __syncthreads();

    s8v breg[5][4];
    #pragma unroll
    for (int kk = 0; kk < 5; ++kk)
        #pragma unroll
        for (int j = 0; j < 4; ++j)
            breg[kk][j] = *(const s8v*)&Bs[wc*64 + j*16 + (lane & 15)]
                                          [kk*32 + (lane >> 4) * 8];

    f32x4 acc[4][4];
    #pragma unroll
    for (int i = 0; i < 4; ++i)
        #pragma unroll
        for (int j = 0; j < 4; ++j) acc[i][j] = (f32x4){0.f, 0.f, 0.f, 0.f};

    #pragma unroll
    for (int kc = 0; kc < 5; ++kc) {
        us8 pa[2];
        int m0 = 0, ko0 = 0, m1 = 0, ko1 = 0;
        if (kc < 4) {
            int f0 = tid;
            m0  = f0 >> 2; ko0 = (f0 & 3) * 8;
            pa[0] = *(const us8*)&A[(size_t)(row0 + m0) * DINT + (kc + 1) * 32 + ko0];
            int f1 = tid + 256;
            m1  = f1 >> 2; ko1 = (f1 & 3) * 8;
            pa[1] = *(const us8*)&A[(size_t)(row0 + m1) * DINT + (kc + 1) * 32 + ko1];
        }

        s8v af[4];
        #pragma unroll
        for (int i = 0; i < 4; ++i)
            af[i] = *(const s8v*)&As[kc & 1][wr*64 + i*16 + (lane & 15)]
                                            [(lane >> 4) * 8];
        #pragma unroll
        for (int i = 0; i < 4; ++i)
            #pragma unroll
            for (int j = 0; j < 4; ++j)
                acc[i][j] = __builtin_amdgcn_mfma_f32_16x16x32_bf16(
                                af[i], breg[kc][j], acc[i][j], 0, 0, 0);

        if (kc < 4) {
            *(us8*)&As[(kc + 1) & 1][m0][ko0] = pa[0];
            *(us8*)&As[(kc + 1) & 1][m1][ko1] = pa[1];
        }
        __syncthreads();
    }

    // ---- C write-out
    #pragma unroll
    for (int i = 0; i < 4; ++i) {
        #pragma unroll
        for (int j = 0; j < 4; ++j) {
            int col  = wc*64 + j*16 + (lane & 15);
            int rowb = row0 + wr*64 + i*16 + ((lane >> 4) << 2);
            #pragma unroll
            for (int q = 0; q < 4; ++q)
                C[(size_t)(rowb + q) * DIN + col] = f2bf(acc[i][j][q]);
        }
    }

    // ---- fused el/er epilogue
    float alv[4], arv[4];
    #pragma unroll
    for (int j = 0; j < 4; ++j) {
        int c = wc*64 + j*16 + (lane & 15);
        alv[j] = al[c];
        arv[j] = ar[c];
    }
    int b0 = lane & 1;
    int b1 = (lane >> 1) & 1;
    #pragma unroll
    for (int i = 0; i < 4; ++i) {
        #pragma unroll
        for (int q = 0; q < 4; ++q) {
            float pl0 = acc[i][0][q]*alv[0] + acc[i][1][q]*alv[1];
            float pl1 = acc[i][2][q]*alv[2] + acc[i][3][q]*alv[3];
            float pr0 = acc[i][0][q]*arv[0] + acc[i][1][q]*arv[1];
            float pr1 = acc[i][2][q]*arv[2] + acc[i][3][q]*arv[3];
            float t;
            t = __shfl_xor(b0 ? pl0 : pl1, 1);
            float vA = (b0 ? pl1 : pl0) + t;
            t = __shfl_xor(b0 ? pr0 : pr1, 1);
            float vB = (b0 ? pr1 : pr0) + t;
            t = __shfl_xor(b1 ? vA : vB, 2);
            float vC = (b1 ? vB : vA) + t;
            vC += __shfl_xor(vC, 4);
            vC += __shfl_xor(vC, 8);
            if ((lane & 12) == 0) {
                int row = row0 + wr*64 + i*16 + ((lane >> 4) << 2) + q;
                int h   = 2*wc + b0;
                if (!b1) {
                    el[(size_t)row * 4 + h] = vC;
                } else if (row < ndst) {
                    er[(size_t)row * 4 + h] = vC;
                }
            }
        }
    }
}

// -------------------------------------------------------------------------
// K3a: per-relation edge softmax + aggregate (RMW into accg). One wave/dst.
// Gathers issued BEFORE softmax to overlap latency. No bias (folded out).
// -------------------------------------------------------------------------
__global__ __launch_bounds__(256) void k_agg_r(
    const ushort_t* __restrict__ proj,   // [nsrc,128] bf16
    const int*      __restrict__ idx,    // [ndst,16]
    const float*    __restrict__ el,     // [nsrc,4]
    const float*    __restrict__ er,     // [ndst,4]
    float*          __restrict__ accg,   // [ndst,128] f32, += per relation
    int ndst)
{
    int wid  = (int)((blockIdx.x * blockDim.x + threadIdx.x) >> 6);
    if (wid >= ndst) return;
    int l    = threadIdx.x & 63;
    int rsub = l >> 4;
    int fg   = l & 15;

    int jv = idx[(size_t)wid * KNB + (l & 15)];

    // issue the 4 row-gathers first (independent of softmax)
    int j2[4];
    us8 v[4];
    #pragma unroll
    for (int kk = 0; kk < 4; ++kk) j2[kk] = __shfl(jv, 4*kk + rsub);
    #pragma unroll
    for (int kk = 0; kk < 4; ++kk)
        v[kk] = *(const us8*)&proj[(size_t)j2[kk] * DIN + fg * 8];

    // softmax over k (lane = k*4 + h)
    int   jk = __shfl(jv, l >> 2);
    float e  = el[(size_t)jk * 4 + (l & 3)] + er[(size_t)wid * 4 + (l & 3)];
    e = e > 0.f ? e : 0.2f * e;
    float mx = e;
    #pragma unroll
    for (int m = 4; m < 64; m <<= 1) mx = fmaxf(mx, __shfl_xor(mx, m));
    float p = __expf(e - mx);
    float s = p;
    #pragma unroll
    for (int m = 4; m < 64; m <<= 1) s += __shfl_xor(s, m);
    float a = p / s;

    float vacc[8];
    #pragma unroll
    for (int t = 0; t < 8; ++t) vacc[t] = 0.f;
    #pragma unroll
    for (int kk = 0; kk < 4; ++kk) {
        float ak = __shfl(a, 16*kk + 4*rsub + (fg >> 2));
        #pragma unroll
        for (int t = 0; t < 8; ++t) vacc[t] = fmaf(ak, bf2f(v[kk][t]), vacc[t]);
    }
    #pragma unroll
    for (int t = 0; t < 8; ++t) {
        vacc[t] += __shfl_xor(vacc[t], 16);
        vacc[t] += __shfl_xor(vacc[t], 32);
    }
    if (l < 16) {
        float* ap = accg + (size_t)wid * DIN + l * 8;
        #pragma unroll
        for (int t = 0; t < 8; ++t) ap[t] += vacc[t];
    }
}

// -------------------------------------------------------------------------
// K3b: batched-R aggregate: wave loops r=0..16, accumulates in registers,
// writes accg once (no memset, no RMW). Needs proj/el/er for ALL r resident.
// -------------------------------------------------------------------------
__global__ __launch_bounds__(256) void k_agg_all(
    const ushort_t* __restrict__ projB,  // [R,nsrc,128] bf16
    const int*      __restrict__ idxB,   // [R,ndst,16]
    const float*    __restrict__ elB,    // [R,nsrc,4]
    const float*    __restrict__ erB,    // [R,ndst,4]
    float*          __restrict__ accg,   // [ndst,128] f32 (overwritten)
    int ndst, int nsrc)
{
    int wid  = (int)((blockIdx.x * blockDim.x + threadIdx.x) >> 6);
    if (wid >= ndst) return;
    int l    = threadIdx.x & 63;
    int rsub = l >> 4;
    int fg   = l & 15;

    float vacc[8];
    #pragma unroll
    for (int t = 0; t < 8; ++t) vacc[t] = 0.f;

    for (int r = 0; r < R; ++r) {
        const ushort_t* proj = projB + (size_t)r * nsrc * DIN;
        const int*      idx  = idxB  + (size_t)r * ndst * KNB;
        const float*    el   = elB   + (size_t)r * nsrc * 4;
        const float*    er   = erB   + (size_t)r * ndst * 4;

        int jv = idx[(size_t)wid * KNB + (l & 15)];

        int j2[4];
        us8 v[4];
        #pragma unroll
        for (int kk = 0; kk < 4; ++kk) j2[kk] = __shfl(jv, 4*kk + rsub);
        #pragma unroll
        for (int kk = 0; kk < 4; ++kk)
            v[kk] = *(const us8*)&proj[(size_t)j2[kk] * DIN + fg * 8];

        int   jk = __shfl(jv, l >> 2);
        float e  = el[(size_t)jk * 4 + (l & 3)] + er[(size_t)wid * 4 + (l & 3)];
        e = e > 0.f ? e : 0.2f * e;
        float mx = e;
        #pragma unroll
        for (int m = 4; m < 64; m <<= 1) mx = fmaxf(mx, __shfl_xor(mx, m));
        float p = __expf(e - mx);
        float s = p;
        #pragma unroll
        for (int m = 4; m < 64; m <<= 1) s += __shfl_xor(s, m);
        float a = p / s;

        #pragma unroll
        for (int kk = 0; kk < 4; ++kk) {
            float ak = __shfl(a, 16*kk + 4*rsub + (fg >> 2));
            #pragma unroll
            for (int t = 0; t < 8; ++t) vacc[t] = fmaf(ak, bf2f(v[kk][t]), vacc[t]);
        }
    }

    #pragma unroll
    for (int t = 0; t < 8; ++t) {
        vacc[t] += __shfl_xor(vacc[t], 16);
        vacc[t] += __shfl_xor(vacc[t], 32);
    }
    if (l < 16) {
        float* ap = accg + (size_t)wid * DIN + l * 8;
        #pragma unroll
        for (int t = 0; t < 8; ++t) ap[t] = vacc[t];
    }
}

// -------------------------------------------------------------------------
// K5: out[t] = relu((acc[root[t/128]][t%128] + bsum1[t%128]) / R)
// -------------------------------------------------------------------------
__global__ __launch_bounds__(256) void k_root(
    const float* __restrict__ acc, const int* __restrict__ root,
    const float* __restrict__ bsum1, float* __restrict__ out, int n)
{
    int t = blockIdx.x * blockDim.x + threadIdx.x;
    if (t < n) {
        float x = acc[(size_t)root[t >> 7] * DIN + (t & 127)] + bsum1[t & 127];
        out[t] = fmaxf(x * (1.f / (float)R), 0.f);
    }
}

// -------------------------------------------------------------------------
extern "C" void kernel_launch(void* const* d_in, const int* in_sizes, int n_in,
                              void* d_out, int out_size, void* d_ws, size_t ws_size,
                              hipStream_t stream)
{
    const float* emb    = (const float*)d_in[0];
    const float* freq   = (const float*)d_in[1];
    const float* phase  = (const float*)d_in[2];
    const float* gamma0 = (const float*)d_in[3];
    const float* beta0  = (const float*)d_in[4];
    const float* W0     = (const float*)d_in[5];
    const float* al0    = (const float*)d_in[6];
    const float* ar0    = (const float*)d_in[7];
    const float* b0     = (const float*)d_in[8];
    const float* gamma1 = (const float*)d_in[9];
    const float* beta1  = (const float*)d_in[10];
    const float* W1     = (const float*)d_in[11];
    const float* al1    = (const float*)d_in[12];
    const float* ar1    = (const float*)d_in[13];
    const float* b1     = (const float*)d_in[14];
    const int* src_ids0 = (const int*)d_in[15];
    const int* src_idx0 = (const int*)d_in[16];
    const int* src_ids1 = (const int*)d_in[17];
    const int* src_idx1 = (const int*)d_in[18];
    const int* root     = (const int*)d_in[19];
    const int* ts       = (const int*)d_in[20];
    float* out = (float*)d_out;

    // ---- workspace carve (byte cursor, 256B aligned)
    char* cur = (char*)d_ws;
    auto carve = [&](size_t bytes) {
        char* p = cur;
        cur += (bytes + 255) & ~(size_t)255;
        return (void*)p;
    };
    ushort_t* hn    = (ushort_t*)carve((size_t)N0 * DINT * 2);
    float*    acc   = (float*)carve((size_t)N1 * DIN * 4);
    ushort_t* wt0   = (ushort_t*)carve((size_t)R * DIN * DINT * 2);
    ushort_t* wt1   = (ushort_t*)carve((size_t)R * DIN * DINT * 2);
    float*    bsum  = (float*)carve(256 * 4);
    ushort_t* proj  = (ushort_t*)carve((size_t)N0 * DIN * 2);   // per-r L0
    float*    el0   = (float*)carve((size_t)N0 * 4 * 4);
    float*    er0   = (float*)carve((size_t)N1 * 4 * 4);
    size_t baseC = (size_t)(cur - (char*)d_ws);
    // batched-L1 extension
    ushort_t* proj1 = (ushort_t*)carve((size_t)R * N1 * DIN * 2);
    float*    el1   = (float*)carve((size_t)R * N1 * 4 * 4);
    float*    er1   = (float*)carve((size_t)R * N2 * 4 * 4);
    size_t needB = (size_t)(cur - (char*)d_ws);
    const bool batchedL1 = (ws_size >= needB);
    (void)baseC;

    const int WTOT = R * DINT * DIN;

    // ---- constants / weights prep
    k_bsum<<<1, 256, 0, stream>>>(b0, b1, bsum);
    k_wcast<<<(WTOT + 255) / 256, 256, 0, stream>>>(W0, wt0, WTOT);
    k_wcast<<<(WTOT + 255) / 256, 256, 0, stream>>>(W1, wt1, WTOT);

    // ---------------- layer 0 (per-relation; keeps proj L3-resident) -------
    hipMemsetAsync(acc, 0, (size_t)N1 * DIN * sizeof(float), stream);
    k_prep<<<N0 / 8, 256, 0, stream>>>(emb, src_ids0, ts, freq, phase,
                                       gamma0, beta0, bsum, hn, N0, 1);
    for (int r = 0; r < R; ++r) {
        k_gemm<<<dim3(N0 / 128, 1), 256, 0, stream>>>(
            hn, wt0 + (size_t)r * DIN * DINT, al0 + r * 128, ar0 + r * 128,
            proj, el0, er0, N1, N0);
        k_agg_r<<<N1 / 4, 256, 0, stream>>>(
            proj, src_idx0 + (size_t)r * N1 * KNB, el0, er0, acc, N1);
    }

    // ---------------- layer 1 ----------------
    k_prep<<<N1 / 8, 256, 0, stream>>>(acc, src_ids1, ts, freq, phase,
                                       gamma1, beta1, bsum, hn, N1, 0);
    if (batchedL1) {
        // one GEMM over all relations, one register-accumulating aggregate
        k_gemm<<<dim3(N1 / 128, R), 256, 0, stream>>>(
            hn, wt1, al1, ar1, proj1, el1, er1, N2, N1);
        k_agg_all<<<N2 / 4, 256, 0, stream>>>(
            proj1, src_idx1, el1, er1, acc, N2, N1);
    } else {
        hipMemsetAsync(acc, 0, (size_t)N2 * DIN * sizeof(float), stream);
        for (int r = 0; r < R; ++r) {
            k_gemm<<<dim3(N1 / 128, 1), 256, 0, stream>>>(
                hn, wt1 + (size_t)r * DIN * DINT, al1 + r * 128, ar1 + r * 128,
                proj, el0, er0, N2, N1);
            k_agg_r<<<N2 / 4, 256, 0, stream>>>(
                proj, src_idx1 + (size_t)r * N2 * KNB, el0, er0, acc, N2);
        }
    }

    // ---------------- root gather (+ bias + relu(x/R)) ----------------
    k_root<<<(N2 * DIN) / 256, 256, 0, stream>>>(acc, root, bsum + 128, out, N2 * DIN);
}